// Round 11
// baseline (2103.289 us; speedup 1.0000x reference)
//
#include <hip/hip_runtime.h>
#include <hip/hip_bf16.h>
#include <stdint.h>

#define N_IN 250000
#define N_OUT 500000
#define INC 256
#define OUTC 128
#define KVOL 8
#define NTOT (KVOL * N_IN)   // 2,000,000 contributions
#define BN_EPS 1e-5f
#define BW_D 128             // d's per bucket
#define NB 3907              // ceil(N_OUT / BW_D)

typedef __bf16 bf16x8_t __attribute__((ext_vector_type(8)));
typedef __bf16 bf16x4_t __attribute__((ext_vector_type(4)));
typedef float f32x4_t __attribute__((ext_vector_type(4)));
typedef uint32_t u32x4_t __attribute__((ext_vector_type(4)));

__device__ __forceinline__ __bf16 f2bf(float x) {
  union { float f; uint32_t u; } v; v.f = x;
  uint32_t r = v.u + 0x7FFFu + ((v.u >> 16) & 1u);
  union { uint16_t s; __bf16 b; } o; o.s = (uint16_t)(r >> 16);
  return o.b;
}

__device__ __forceinline__ uint32_t pack2bf(float lo, float hi) {
  union { float f; uint32_t u; } a, b; a.f = lo; b.f = hi;
  uint32_t ra = a.u + 0x7FFFu + ((a.u >> 16) & 1u);
  uint32_t rb = b.u + 0x7FFFu + ((b.u >> 16) & 1u);
  return (ra >> 16) | (rb & 0xFFFF0000u);
}

__device__ __forceinline__ float bflo(uint32_t w) {
  union { uint32_t u; float f; } v; v.u = w << 16; return v.f;
}
__device__ __forceinline__ float bfhi(uint32_t w) {
  union { uint32_t u; float f; } v; v.u = w & 0xFFFF0000u; return v.f;
}

// W[k][inc][outc] fp32 -> Wt[k][outc][inc] bf16 (contiguous MFMA fragments)
__global__ void wconv_kernel(const float* __restrict__ W, __bf16* __restrict__ Wt) {
  int f = blockIdx.x * blockDim.x + threadIdx.x;
  if (f >= KVOL * OUTC * INC) return;
  int i = f & (INC - 1);
  int o = (f >> 8) & (OUTC - 1);
  int k = f >> 15;
  Wt[f] = f2bf(W[(k * INC + i) * OUTC + o]);
}

// ======================= bucket histogram + scan =======================

__global__ void histb_kernel(const int* __restrict__ oidx, int* __restrict__ cnt) {
  int g = blockIdx.x * 256 + threadIdx.x;
  if (g < NTOT) atomicAdd(&cnt[oidx[g] >> 7], 1);
}

// single-block scan of NB bucket counts -> base (immutable) + cur (cursors)
__global__ void scanb_kernel(const int* __restrict__ cnt, int* __restrict__ base,
                             int* __restrict__ cur) {
  __shared__ int sd[512];
  int t = threadIdx.x;
  int v[8]; int sm = 0;
  #pragma unroll
  for (int e = 0; e < 8; ++e) {
    int idx = t * 8 + e;
    v[e] = (idx < NB) ? cnt[idx] : 0;
    sm += v[e];
  }
  sd[t] = sm; __syncthreads();
  for (int o = 1; o < 512; o <<= 1) {
    int a = (t >= o) ? sd[t - o] : 0;
    __syncthreads();
    sd[t] += a;
    __syncthreads();
  }
  int excl = sd[t] - sm;
  #pragma unroll
  for (int e = 0; e < 8; ++e) {
    int idx = t * 8 + e;
    if (idx < NB) { base[idx] = excl; cur[idx] = excl; }
    excl += v[e];
  }
  if (t == 511) base[NB] = NTOT;
}

// ======================= GEMM -> bucket-binned partials =======================

#define TM 64
#define LDS_STRIDE 264  // bf16 elems per xs row (256 + 8 pad)

// 512 threads = 8 waves; wave w handles kernel offset k=w (R8 structure).
// Each output row's destination comes from a bucket-cursor atomicAdd
// (bucket = d>>7) -> writes append to ~3907 sequential stream heads.
__global__ __launch_bounds__(512, 1) void gemm_bin_kernel(
    const float* __restrict__ x, const __bf16* __restrict__ Wt,
    const int* __restrict__ oidx, int* __restrict__ cur,
    int* __restrict__ tag, char* __restrict__ partials) {
  __shared__ __bf16 xs[TM * LDS_STRIDE];              // 33792 B
  __shared__ __align__(16) uint2 stg[8][16][34];      // 34816 B
  const int t = threadIdx.x;
  const int row0 = blockIdx.x * TM;

  // ---- stage x tile (64 x 256 fp32 -> bf16 LDS), nt loads ----
  #pragma unroll
  for (int i = 0; i < 8; ++i) {
    int f = t + i * 512;
    int r = f >> 6;
    int c4 = f & 63;
    int grow = row0 + r;
    f32x4_t v = {0.f, 0.f, 0.f, 0.f};
    if (grow < N_IN)
      v = __builtin_nontemporal_load((const f32x4_t*)x + (size_t)grow * 64 + c4);
    bf16x4_t bv;
    bv[0] = f2bf(v[0]); bv[1] = f2bf(v[1]); bv[2] = f2bf(v[2]); bv[3] = f2bf(v[3]);
    *(bf16x4_t*)&xs[r * LDS_STRIDE + c4 * 4] = bv;
  }
  __syncthreads();

  const int w  = t >> 6;
  const int l  = t & 63;
  const int lr = l & 15;
  const int lg = l >> 4;

  f32x4_t accT[8][4];
  #pragma unroll
  for (int n = 0; n < 8; ++n)
    #pragma unroll
    for (int m = 0; m < 4; ++m)
      accT[n][m] = (f32x4_t){0.f, 0.f, 0.f, 0.f};

  const __bf16* Wk = Wt + (size_t)w * OUTC * INC;

  #pragma unroll
  for (int s = 0; s < 8; ++s) {
    bf16x8_t a[4], b[8];
    #pragma unroll
    for (int m = 0; m < 4; ++m)
      a[m] = *(const bf16x8_t*)&xs[(m * 16 + lr) * LDS_STRIDE + s * 32 + lg * 8];
    #pragma unroll
    for (int n = 0; n < 8; ++n)
      b[n] = *(const bf16x8_t*)&Wk[(n * 16 + lr) * INC + s * 32 + lg * 8];
    // swapped operands -> D[chan][voxel]
    #pragma unroll
    for (int n = 0; n < 8; ++n)
      #pragma unroll
      for (int m = 0; m < 4; ++m)
        accT[n][m] = __builtin_amdgcn_mfma_f32_16x16x32_bf16(b[n], a[m], accT[n][m], 0, 0, 0);
  }

  // ---- per-wave staged store: cursor-bump destination, no block barriers ----
  const int r2 = l >> 2;         // row within the 16-row subtile
  const int p  = l & 3;          // 64B quarter of the 256B row
  #pragma unroll
  for (int m = 0; m < 4; ++m) {
    #pragma unroll
    for (int n = 0; n < 8; ++n) {
      uint2 pk;
      pk.x = pack2bf(accT[n][m][0], accT[n][m][1]);
      pk.y = pack2bf(accT[n][m][2], accT[n][m][3]);
      stg[w][lr][n * 4 + lg] = pk;
    }
    asm volatile("s_waitcnt lgkmcnt(0)" ::: "memory");
    __builtin_amdgcn_wave_barrier();
    int grow = row0 + m * 16 + r2;
    int pos = 0;
    if (grow < N_IN) {
      int d = oidx[w * N_IN + grow];            // 4 lanes same addr -> broadcast
      if (p == 0) {
        pos = atomicAdd(&cur[d >> 7], 1);
        tag[pos] = d;
      }
    }
    pos = __shfl(pos, l & 60, 64);              // broadcast from p==0 lane
    if (grow < N_IN) {
      const u32x4_t* rp = (const u32x4_t*)&stg[w][r2][0];
      char* dst = partials + (size_t)pos * 256 + p * 64;
      #pragma unroll
      for (int q = 0; q < 4; ++q)
        *(u32x4_t*)(dst + q * 16) = rp[p * 4 + q];
    }
    __builtin_amdgcn_wave_barrier();
  }
}

// ============== bucket reduce: LDS f32 accumulate + fused BN stats ==============

// grid (NB); 512 thr. Block b: read its contiguous partials run sequentially,
// ds-atomic-accumulate into acc[128][132] f32, then pack rows to d_out slots
// and accumulate rounded-value stats.
__global__ __launch_bounds__(512, 2) void bucket_reduce_kernel(
    const char* __restrict__ partials, const int* __restrict__ tag,
    const int* __restrict__ base, char* __restrict__ accb, float* __restrict__ stats) {
  __shared__ float acc[BW_D][132];   // 67,584 B (stride 132: de-phase bank groups)
  __shared__ float reds[4][128];
  __shared__ float redq[4][128];
  const int t = threadIdx.x;
  const int b = blockIdx.x;
  const int d0 = b * BW_D;
  const int j0 = base[b], j1 = base[b + 1];

  for (int i = t; i < BW_D * 132; i += 512) ((float*)acc)[i] = 0.f;
  __syncthreads();

  const int lane16 = t & 15;
  const int grp = t >> 4;   // 0..31
  for (int j = j0 + grp; j < j1; j += 32) {
    int di = tag[j] - d0;
    u32x4_t v = __builtin_nontemporal_load(
        (const u32x4_t*)(partials + (size_t)j * 256 + lane16 * 16));
    float* ap = &acc[di][lane16 * 8];
    atomicAdd(&ap[0], bflo(v[0])); atomicAdd(&ap[1], bfhi(v[0]));
    atomicAdd(&ap[2], bflo(v[1])); atomicAdd(&ap[3], bfhi(v[1]));
    atomicAdd(&ap[4], bflo(v[2])); atomicAdd(&ap[5], bfhi(v[2]));
    atomicAdd(&ap[6], bflo(v[3])); atomicAdd(&ap[7], bfhi(v[3]));
  }
  __syncthreads();

  // pack + write output rows: 4 threads per row, 32 channels (64 B) each
  {
    int di = t >> 2, q = t & 3;
    int d = d0 + di;
    if (d < N_OUT) {
      uint32_t wbuf[16];
      #pragma unroll
      for (int wi = 0; wi < 16; ++wi) {
        int c = q * 32 + wi * 2;
        wbuf[wi] = pack2bf(acc[di][c], acc[di][c + 1]);
      }
      char* dst = accb + (size_t)d * 512 + q * 64;
      *(u32x4_t*)dst        = *(u32x4_t*)&wbuf[0];
      *(u32x4_t*)(dst + 16) = *(u32x4_t*)&wbuf[4];
      *(u32x4_t*)(dst + 32) = *(u32x4_t*)&wbuf[8];
      *(u32x4_t*)(dst + 48) = *(u32x4_t*)&wbuf[12];
    }
  }

  // stats on rounded values (zeros of empty rows contribute nothing)
  {
    int c = t & 127, gr = t >> 7;   // 4 groups
    float sm = 0.f, sq = 0.f;
    for (int di = gr; di < BW_D; di += 4) {
      if (d0 + di < N_OUT) {
        float rv = bflo(pack2bf(acc[di][c], 0.f));
        sm += rv; sq += rv * rv;
      }
    }
    reds[gr][c] = sm; redq[gr][c] = sq;
  }
  __syncthreads();
  if (t < 128) {
    atomicAdd(&stats[t], reds[0][t] + reds[1][t] + reds[2][t] + reds[3][t]);
  } else if (t < 256) {
    int c = t - 128;
    atomicAdd(&stats[128 + c], redq[0][c] + redq[1][c] + redq[2][c] + redq[3][c]);
  }
}

// Read bf16 accum from row slot, write normalized fp32 over the full slot (nt).
__global__ void norm_kernel(char* __restrict__ outb, const float* __restrict__ stats,
                            const float* __restrict__ gamma, const float* __restrict__ beta) {
  const int t = threadIdx.x;
  const int j = t & 15;
  const int ro = t >> 4;
  const float inv_n = 1.0f / (float)N_OUT;
  float sc[8], sh[8];
  #pragma unroll
  for (int i = 0; i < 8; ++i) {
    int c = j * 8 + i;
    float mean = stats[c] * inv_n;
    float var  = stats[128 + c] * inv_n - mean * mean;
    float s = gamma[c] * rsqrtf(var + BN_EPS);
    sc[i] = s;
    sh[i] = beta[c] - mean * s;
  }
  for (int r = blockIdx.x * 16 + ro; r < N_OUT; r += gridDim.x * 16) {
    u32x4_t v = *(const u32x4_t*)(outb + (size_t)r * 512 + j * 16);
    f32x4_t o0, o1;
    #pragma unroll
    for (int u = 0; u < 4; ++u) {
      float f0 = bflo(v[u]) * sc[2 * u] + sh[2 * u];
      float f1 = bfhi(v[u]) * sc[2 * u + 1] + sh[2 * u + 1];
      if (u < 2) { o0[2 * u] = f0; o0[2 * u + 1] = f1; }
      else       { o1[2 * (u - 2)] = f0; o1[2 * (u - 2) + 1] = f1; }
    }
    __builtin_nontemporal_store(o0, (f32x4_t*)(outb + (size_t)r * 512 + j * 32));
    __builtin_nontemporal_store(o1, (f32x4_t*)(outb + (size_t)r * 512 + j * 32 + 16));
  }
}

// ======================= fallback (round-2 proven atomic path) =======================

__global__ __launch_bounds__(512, 1) void gemm_scatter_f32_kernel(
    const float* __restrict__ x, const __bf16* __restrict__ Wt,
    const int* __restrict__ out_idx, float* __restrict__ acc) {
  __shared__ __bf16 xs[TM * LDS_STRIDE];
  const int t = threadIdx.x;
  const int row0 = blockIdx.x * TM;
  #pragma unroll
  for (int i = 0; i < 8; ++i) {
    int f = t + i * 512;
    int r = f >> 6;
    int c4 = f & 63;
    int grow = row0 + r;
    float4 v = make_float4(0.f, 0.f, 0.f, 0.f);
    if (grow < N_IN) v = ((const float4*)x)[(size_t)grow * 64 + c4];
    bf16x4_t bv;
    bv[0] = f2bf(v.x); bv[1] = f2bf(v.y); bv[2] = f2bf(v.z); bv[3] = f2bf(v.w);
    *(bf16x4_t*)&xs[r * LDS_STRIDE + c4 * 4] = bv;
  }
  __syncthreads();
  const int w = t >> 6, l = t & 63, lr = l & 15, lg = l >> 4;
  f32x4_t accr[4][8];
  #pragma unroll
  for (int m = 0; m < 4; ++m)
    #pragma unroll
    for (int n = 0; n < 8; ++n)
      accr[m][n] = (f32x4_t){0.f, 0.f, 0.f, 0.f};
  const __bf16* Wkp = Wt + (size_t)w * OUTC * INC;
  #pragma unroll
  for (int s = 0; s < 8; ++s) {
    bf16x8_t a[4], b[8];
    #pragma unroll
    for (int m = 0; m < 4; ++m)
      a[m] = *(const bf16x8_t*)&xs[(m * 16 + lr) * LDS_STRIDE + s * 32 + lg * 8];
    #pragma unroll
    for (int n = 0; n < 8; ++n)
      b[n] = *(const bf16x8_t*)&Wkp[(n * 16 + lr) * INC + s * 32 + lg * 8];
    #pragma unroll
    for (int m = 0; m < 4; ++m)
      #pragma unroll
      for (int n = 0; n < 8; ++n)
        accr[m][n] = __builtin_amdgcn_mfma_f32_16x16x32_bf16(a[m], b[n], accr[m][n], 0, 0, 0);
  }
  const int* oidx = out_idx + (size_t)w * N_IN;
  #pragma unroll
  for (int m = 0; m < 4; ++m) {
    int rbase = m * 16 + lg * 4;
    #pragma unroll
    for (int reg = 0; reg < 4; ++reg) {
      int grow = row0 + rbase + reg;
      if (grow < N_IN) {
        int dst = oidx[grow];
        float* ap = acc + (size_t)dst * OUTC;
        #pragma unroll
        for (int n = 0; n < 8; ++n)
          atomicAdd(&ap[n * 16 + lr], accr[m][n][reg]);
      }
    }
  }
}

__global__ void stats_f32_kernel(const float* __restrict__ acc, float* __restrict__ stats) {
  const int t = threadIdx.x;
  const int c4 = t & 31;
  const int ro = t >> 5;
  f32x4_t s = {0.f, 0.f, 0.f, 0.f}, q = {0.f, 0.f, 0.f, 0.f};
  for (int r = blockIdx.x * 8 + ro; r < N_OUT; r += gridDim.x * 8) {
    f32x4_t v = ((const f32x4_t*)acc)[(size_t)r * 32 + c4];
    s += v; q += v * v;
  }
  __shared__ float redl[256][8];
  #pragma unroll
  for (int j = 0; j < 4; ++j) { redl[t][j] = s[j]; redl[t][4 + j] = q[j]; }
  __syncthreads();
  if (t < 32) {
    float S[4] = {0.f, 0.f, 0.f, 0.f}, Q[4] = {0.f, 0.f, 0.f, 0.f};
    for (int r2 = 0; r2 < 8; ++r2)
      #pragma unroll
      for (int j = 0; j < 4; ++j) {
        S[j] += redl[r2 * 32 + t][j];
        Q[j] += redl[r2 * 32 + t][4 + j];
      }
    #pragma unroll
    for (int j = 0; j < 4; ++j) {
      atomicAdd(&stats[t * 4 + j], S[j]);
      atomicAdd(&stats[128 + t * 4 + j], Q[j]);
    }
  }
}

__global__ void norm_f32_kernel(float* __restrict__ out, const float* __restrict__ stats,
                                const float* __restrict__ gamma, const float* __restrict__ beta) {
  const int t = threadIdx.x;
  const int c4 = t & 31;
  const int ro = t >> 5;
  const float inv_n = 1.0f / (float)N_OUT;
  float sc[4], sh[4];
  #pragma unroll
  for (int j = 0; j < 4; ++j) {
    int c = c4 * 4 + j;
    float mean = stats[c] * inv_n;
    float var  = stats[128 + c] * inv_n - mean * mean;
    float s = gamma[c] * rsqrtf(var + BN_EPS);
    sc[j] = s;
    sh[j] = beta[c] - mean * s;
  }
  for (int r = blockIdx.x * 8 + ro; r < N_OUT; r += gridDim.x * 8) {
    f32x4_t v = ((const f32x4_t*)out)[(size_t)r * 32 + c4];
    #pragma unroll
    for (int j = 0; j < 4; ++j) v[j] = v[j] * sc[j] + sh[j];
    ((f32x4_t*)out)[(size_t)r * 32 + c4] = v;
  }
}

// ======================= launch =======================

extern "C" void kernel_launch(void* const* d_in, const int* in_sizes, int n_in,
                              void* d_out, int out_size, void* d_ws, size_t ws_size,
                              hipStream_t stream) {
  const float* x     = (const float*)d_in[0];
  const float* W     = (const float*)d_in[1];
  const float* gamma = (const float*)d_in[2];
  const float* beta  = (const float*)d_in[3];
  const int*   oidx  = (const int*)d_in[4];

  // ws layout (~520.6 MB; 526.5 MB proven available)
  const size_t PART_OFF  = 0;              // 512,000,000
  const size_t TAG_OFF   = 512000000;      //   8,000,000
  const size_t CNT_OFF   = 520000000;      //      16,384
  const size_t BASE_OFF  = 520016384;      //      16,384 (NB+1 ints)
  const size_t CUR_OFF   = 520032768;      //      16,384
  const size_t WT_OFF    = 520049152;      //     524,288
  const size_t STATS_OFF = 520573440;      //       1,024
  const size_t NEED      = 520574464;

  if (ws_size >= NEED) {
    char* ws = (char*)d_ws;
    char* partials = ws + PART_OFF;
    int* tag     = (int*)(ws + TAG_OFF);
    int* cnt     = (int*)(ws + CNT_OFF);
    int* base    = (int*)(ws + BASE_OFF);
    int* cur     = (int*)(ws + CUR_OFF);
    __bf16* Wt   = (__bf16*)(ws + WT_OFF);
    float* stats = (float*)(ws + STATS_OFF);

    hipMemsetAsync(cnt, 0, NB * sizeof(int), stream);
    hipMemsetAsync(stats, 0, 256 * sizeof(float), stream);

    wconv_kernel<<<(KVOL * OUTC * INC + 255) / 256, 256, 0, stream>>>(W, Wt);
    histb_kernel<<<(NTOT + 255) / 256, 256, 0, stream>>>(oidx, cnt);
    scanb_kernel<<<1, 512, 0, stream>>>(cnt, base, cur);
    gemm_bin_kernel<<<(N_IN + TM - 1) / TM, 512, 0, stream>>>(
        x, Wt, oidx, cur, tag, partials);
    bucket_reduce_kernel<<<NB, 512, 0, stream>>>(
        partials, tag, base, (char*)d_out, stats);
    norm_kernel<<<512, 256, 0, stream>>>((char*)d_out, stats, gamma, beta);
  } else {
    // fallback: proven round-2 atomic pipeline (~526 KB ws)
    __bf16* Wt   = (__bf16*)d_ws;
    float* stats = (float*)((char*)d_ws + (size_t)KVOL * OUTC * INC * 2);
    float* out = (float*)d_out;

    hipMemsetAsync(d_out, 0, (size_t)N_OUT * OUTC * sizeof(float), stream);
    hipMemsetAsync(stats, 0, 256 * sizeof(float), stream);

    wconv_kernel<<<(KVOL * OUTC * INC + 255) / 256, 256, 0, stream>>>(W, Wt);
    gemm_scatter_f32_kernel<<<(N_IN + TM - 1) / TM, 512, 0, stream>>>(x, Wt, oidx, out);
    stats_f32_kernel<<<1024, 256, 0, stream>>>(out, stats);
    norm_f32_kernel<<<2048, 256, 0, stream>>>(out, stats, gamma, beta);
  }
}

// Round 12
// 802.050 us; speedup vs baseline: 2.6224x; 2.6224x over previous
//
#include <hip/hip_runtime.h>
#include <hip/hip_bf16.h>
#include <stdint.h>

#define N_IN 250000
#define N_OUT 500000
#define INC 256
#define OUTC 128
#define KVOL 8
#define NTOT (KVOL * N_IN)   // 2,000,000 contributions
#define BN_EPS 1e-5f

typedef __bf16 bf16x8_t __attribute__((ext_vector_type(8)));
typedef __bf16 bf16x4_t __attribute__((ext_vector_type(4)));
typedef float f32x4_t __attribute__((ext_vector_type(4)));
typedef uint32_t u32x4_t __attribute__((ext_vector_type(4)));

__device__ __forceinline__ __bf16 f2bf(float x) {
  union { float f; uint32_t u; } v; v.f = x;
  uint32_t r = v.u + 0x7FFFu + ((v.u >> 16) & 1u);
  union { uint16_t s; __bf16 b; } o; o.s = (uint16_t)(r >> 16);
  return o.b;
}

__device__ __forceinline__ uint32_t pack2bf(float lo, float hi) {
  union { float f; uint32_t u; } a, b; a.f = lo; b.f = hi;
  uint32_t ra = a.u + 0x7FFFu + ((a.u >> 16) & 1u);
  uint32_t rb = b.u + 0x7FFFu + ((b.u >> 16) & 1u);
  return (ra >> 16) | (rb & 0xFFFF0000u);
}

__device__ __forceinline__ float bflo(uint32_t w) {
  union { uint32_t u; float f; } v; v.u = w << 16; return v.f;
}
__device__ __forceinline__ float bfhi(uint32_t w) {
  union { uint32_t u; float f; } v; v.u = w & 0xFFFF0000u; return v.f;
}

// W[k][inc][outc] fp32 -> Wt[k][outc][inc] bf16 (contiguous MFMA fragments)
__global__ void wconv_kernel(const float* __restrict__ W, __bf16* __restrict__ Wt) {
  int f = blockIdx.x * blockDim.x + threadIdx.x;
  if (f >= KVOL * OUTC * INC) return;
  int i = f & (INC - 1);
  int o = (f >> 8) & (OUTC - 1);
  int k = f >> 15;
  Wt[f] = f2bf(W[(k * INC + i) * OUTC + o]);
}

// ======================= counting-sort passes (global d-order) =======================

__global__ void hist_kernel(const int* __restrict__ oidx, int* __restrict__ cnt) {
  int g = blockIdx.x * 256 + threadIdx.x;
  if (g < NTOT) atomicAdd(&cnt[oidx[g]], 1);
}

// per-1024-chunk exclusive scan + chunk totals
__global__ void scan1_kernel(const int* __restrict__ cnt, int* __restrict__ offs,
                             int* __restrict__ bsum) {
  __shared__ int sd[256];
  int t = threadIdx.x;
  int base = blockIdx.x * 1024 + t * 4;
  int v0 = 0, v1 = 0, v2 = 0, v3 = 0;
  if (base + 3 < N_OUT) {
    int4 v = *(const int4*)&cnt[base];
    v0 = v.x; v1 = v.y; v2 = v.z; v3 = v.w;
  } else {
    if (base     < N_OUT) v0 = cnt[base];
    if (base + 1 < N_OUT) v1 = cnt[base + 1];
    if (base + 2 < N_OUT) v2 = cnt[base + 2];
  }
  int s = v0 + v1 + v2 + v3;
  sd[t] = s; __syncthreads();
  for (int o = 1; o < 256; o <<= 1) {
    int a = (t >= o) ? sd[t - o] : 0;
    __syncthreads();
    sd[t] += a;
    __syncthreads();
  }
  int excl = sd[t] - s;
  if (base     < N_OUT) offs[base]     = excl;
  if (base + 1 < N_OUT) offs[base + 1] = excl + v0;
  if (base + 2 < N_OUT) offs[base + 2] = excl + v0 + v1;
  if (base + 3 < N_OUT) offs[base + 3] = excl + v0 + v1 + v2;
  if (t == 255) bsum[blockIdx.x] = sd[255];
}

// single-block exclusive scan of chunk totals (nb <= 512)
__global__ void scan2_kernel(const int* __restrict__ bsum, int* __restrict__ bsumx, int nb) {
  __shared__ int sd[512];
  int t = threadIdx.x;
  int s = (t < nb) ? bsum[t] : 0;
  sd[t] = s; __syncthreads();
  for (int o = 1; o < 512; o <<= 1) {
    int a = (t >= o) ? sd[t - o] : 0;
    __syncthreads();
    sd[t] += a;
    __syncthreads();
  }
  if (t < nb) bsumx[t] = sd[t] - s;
}

// finalize offs (+sentinel) and the gemm's claim-cursors
__global__ void scan3_kernel(int* __restrict__ offs, int* __restrict__ cursor,
                             const int* __restrict__ bsumx) {
  int g = blockIdx.x * 256 + threadIdx.x;
  if (g < N_OUT) {
    int v = offs[g] + bsumx[g >> 10];
    offs[g] = v;
    cursor[g] = v;
  }
  if (g == 0) offs[N_OUT] = NTOT;
}

// ======================= GEMM -> d-sorted partials (fused slot claim) =======================

#define TM 64
#define LDS_STRIDE 264  // bf16 elems per xs row (256 + 8 pad)

// 512 threads = 8 waves; wave w handles kernel offset k=w. Computes the
// transposed product D[chan][voxel]; per-wave LDS staging (wave-synchronous,
// no block barriers in the store loop); each row CLAIMS its d-sorted slot via
// cursor atomicAdd (arbitrary order within a d-run is fine for summation).
__global__ __launch_bounds__(512, 1) void gemm_store_kernel(
    const float* __restrict__ x, const __bf16* __restrict__ Wt,
    const int* __restrict__ oidx, int* __restrict__ cursor,
    char* __restrict__ partials) {
  __shared__ __bf16 xs[TM * LDS_STRIDE];              // 33792 B
  __shared__ __align__(16) uint2 stg[8][16][34];      // 34816 B, 272B row stride
  const int t = threadIdx.x;
  const int row0 = blockIdx.x * TM;

  // ---- stage x tile (64 x 256 fp32 -> bf16 LDS), nt loads, zero-fill OOB ----
  #pragma unroll
  for (int i = 0; i < 8; ++i) {
    int f = t + i * 512;
    int r = f >> 6;
    int c4 = f & 63;
    int grow = row0 + r;
    f32x4_t v = {0.f, 0.f, 0.f, 0.f};
    if (grow < N_IN)
      v = __builtin_nontemporal_load((const f32x4_t*)x + (size_t)grow * 64 + c4);
    bf16x4_t bv;
    bv[0] = f2bf(v[0]); bv[1] = f2bf(v[1]); bv[2] = f2bf(v[2]); bv[3] = f2bf(v[3]);
    *(bf16x4_t*)&xs[r * LDS_STRIDE + c4 * 4] = bv;
  }
  __syncthreads();

  const int w  = t >> 6;
  const int l  = t & 63;
  const int lr = l & 15;
  const int lg = l >> 4;

  f32x4_t accT[8][4];
  #pragma unroll
  for (int n = 0; n < 8; ++n)
    #pragma unroll
    for (int m = 0; m < 4; ++m)
      accT[n][m] = (f32x4_t){0.f, 0.f, 0.f, 0.f};

  const __bf16* Wk = Wt + (size_t)w * OUTC * INC;

  #pragma unroll
  for (int s = 0; s < 8; ++s) {
    bf16x8_t a[4], b[8];
    #pragma unroll
    for (int m = 0; m < 4; ++m)
      a[m] = *(const bf16x8_t*)&xs[(m * 16 + lr) * LDS_STRIDE + s * 32 + lg * 8];
    #pragma unroll
    for (int n = 0; n < 8; ++n)
      b[n] = *(const bf16x8_t*)&Wk[(n * 16 + lr) * INC + s * 32 + lg * 8];
    // swapped operands -> D[chan][voxel]
    #pragma unroll
    for (int n = 0; n < 8; ++n)
      #pragma unroll
      for (int m = 0; m < 4; ++m)
        accT[n][m] = __builtin_amdgcn_mfma_f32_16x16x32_bf16(b[n], a[m], accT[n][m], 0, 0, 0);
  }

  // ---- per-wave staged store: claim slot via cursor, no block barriers ----
  // lane (lg,lr) holds voxel m*16+lr, chans n*16+lg*4+{0..3}
  const int r2 = l >> 2;         // row within the 16-row subtile
  const int p  = l & 3;          // 64B quarter of the 256B row
  #pragma unroll
  for (int m = 0; m < 4; ++m) {
    #pragma unroll
    for (int n = 0; n < 8; ++n) {
      uint2 pk;
      pk.x = pack2bf(accT[n][m][0], accT[n][m][1]);
      pk.y = pack2bf(accT[n][m][2], accT[n][m][3]);
      stg[w][lr][n * 4 + lg] = pk;
    }
    // wave-internal LDS write->read ordering (per-wave buffer, lockstep wave)
    asm volatile("s_waitcnt lgkmcnt(0)" ::: "memory");
    __builtin_amdgcn_wave_barrier();
    int grow = row0 + m * 16 + r2;
    int pos = 0;
    if (grow < N_IN && p == 0)
      pos = atomicAdd(&cursor[oidx[w * N_IN + grow]], 1);
    pos = __shfl(pos, l & 60, 64);   // broadcast from the quad's p==0 lane
    if (grow < N_IN) {
      const u32x4_t* rp = (const u32x4_t*)&stg[w][r2][0];
      char* dst = partials + (size_t)pos * 256 + p * 64;
      #pragma unroll
      for (int q = 0; q < 4; ++q)
        *(u32x4_t*)(dst + q * 16) = rp[p * 4 + q];
    }
    __builtin_amdgcn_wave_barrier();
  }
}

// ============== segmented reduce + fused BN stats ==============

// 256 thr = 16 groups x 16 lanes; group handles one output row at a time:
// sums its contiguous partials (nt loads: read-once), writes bf16 accum into
// d_out slot, and accumulates per-channel sum/sumsq over the rounded values.
__global__ __launch_bounds__(256) void reduce_stats_kernel(
    const char* __restrict__ partials, const int* __restrict__ offs,
    char* __restrict__ accb, float* __restrict__ stats) {
  const int t = threadIdx.x;
  const int lane16 = t & 15;
  const int grp = t >> 4;
  float s[8], q[8];
  #pragma unroll
  for (int i = 0; i < 8; ++i) { s[i] = 0.f; q[i] = 0.f; }

  for (int d = blockIdx.x * 16 + grp; d < N_OUT; d += gridDim.x * 16) {
    int j0 = offs[d], j1 = offs[d + 1];
    float a[8];
    #pragma unroll
    for (int i = 0; i < 8; ++i) a[i] = 0.f;
    for (int j = j0; j < j1; ++j) {
      u32x4_t v = __builtin_nontemporal_load(
          (const u32x4_t*)(partials + (size_t)j * 256 + lane16 * 16));
      a[0] += bflo(v[0]); a[1] += bfhi(v[0]);
      a[2] += bflo(v[1]); a[3] += bfhi(v[1]);
      a[4] += bflo(v[2]); a[5] += bfhi(v[2]);
      a[6] += bflo(v[3]); a[7] += bfhi(v[3]);
    }
    u32x4_t o;
    o[0] = pack2bf(a[0], a[1]); o[1] = pack2bf(a[2], a[3]);
    o[2] = pack2bf(a[4], a[5]); o[3] = pack2bf(a[6], a[7]);
    *(u32x4_t*)(accb + (size_t)d * 512 + lane16 * 16) = o;
    #pragma unroll
    for (int u = 0; u < 4; ++u) {
      float f0 = bflo(o[u]), f1 = bfhi(o[u]);
      s[2 * u] += f0;     q[2 * u] += f0 * f0;
      s[2 * u + 1] += f1; q[2 * u + 1] += f1 * f1;
    }
  }

  __shared__ float reds[16][16][8];
  __shared__ float redq[16][16][8];
  #pragma unroll
  for (int i = 0; i < 8; ++i) { reds[grp][lane16][i] = s[i]; redq[grp][lane16][i] = q[i]; }
  __syncthreads();
  if (t < 128) {
    float acc = 0.f;
    #pragma unroll
    for (int g2 = 0; g2 < 16; ++g2) acc += reds[g2][t >> 3][t & 7];
    atomicAdd(&stats[t], acc);
  } else {
    int c = t - 128;
    float acc = 0.f;
    #pragma unroll
    for (int g2 = 0; g2 < 16; ++g2) acc += redq[g2][c >> 3][c & 7];
    atomicAdd(&stats[128 + c], acc);
  }
}

// Read bf16 accum from row slot, write normalized fp32 over the full slot (nt).
__global__ void norm_kernel(char* __restrict__ outb, const float* __restrict__ stats,
                            const float* __restrict__ gamma, const float* __restrict__ beta) {
  const int t = threadIdx.x;
  const int j = t & 15;
  const int ro = t >> 4;
  const float inv_n = 1.0f / (float)N_OUT;
  float sc[8], sh[8];
  #pragma unroll
  for (int i = 0; i < 8; ++i) {
    int c = j * 8 + i;
    float mean = stats[c] * inv_n;
    float var  = stats[128 + c] * inv_n - mean * mean;
    float s = gamma[c] * rsqrtf(var + BN_EPS);
    sc[i] = s;
    sh[i] = beta[c] - mean * s;
  }
  for (int r = blockIdx.x * 16 + ro; r < N_OUT; r += gridDim.x * 16) {
    u32x4_t v = *(const u32x4_t*)(outb + (size_t)r * 512 + j * 16);
    f32x4_t o0, o1;
    #pragma unroll
    for (int u = 0; u < 4; ++u) {
      float f0 = bflo(v[u]) * sc[2 * u] + sh[2 * u];
      float f1 = bfhi(v[u]) * sc[2 * u + 1] + sh[2 * u + 1];
      if (u < 2) { o0[2 * u] = f0; o0[2 * u + 1] = f1; }
      else       { o1[2 * (u - 2)] = f0; o1[2 * (u - 2) + 1] = f1; }
    }
    __builtin_nontemporal_store(o0, (f32x4_t*)(outb + (size_t)r * 512 + j * 32));
    __builtin_nontemporal_store(o1, (f32x4_t*)(outb + (size_t)r * 512 + j * 32 + 16));
  }
}

// ======================= fallback (round-2 proven atomic path) =======================

__global__ __launch_bounds__(512, 1) void gemm_scatter_f32_kernel(
    const float* __restrict__ x, const __bf16* __restrict__ Wt,
    const int* __restrict__ out_idx, float* __restrict__ acc) {
  __shared__ __bf16 xs[TM * LDS_STRIDE];
  const int t = threadIdx.x;
  const int row0 = blockIdx.x * TM;
  #pragma unroll
  for (int i = 0; i < 8; ++i) {
    int f = t + i * 512;
    int r = f >> 6;
    int c4 = f & 63;
    int grow = row0 + r;
    float4 v = make_float4(0.f, 0.f, 0.f, 0.f);
    if (grow < N_IN) v = ((const float4*)x)[(size_t)grow * 64 + c4];
    bf16x4_t bv;
    bv[0] = f2bf(v.x); bv[1] = f2bf(v.y); bv[2] = f2bf(v.z); bv[3] = f2bf(v.w);
    *(bf16x4_t*)&xs[r * LDS_STRIDE + c4 * 4] = bv;
  }
  __syncthreads();
  const int w = t >> 6, l = t & 63, lr = l & 15, lg = l >> 4;
  f32x4_t accr[4][8];
  #pragma unroll
  for (int m = 0; m < 4; ++m)
    #pragma unroll
    for (int n = 0; n < 8; ++n)
      accr[m][n] = (f32x4_t){0.f, 0.f, 0.f, 0.f};
  const __bf16* Wkp = Wt + (size_t)w * OUTC * INC;
  #pragma unroll
  for (int s = 0; s < 8; ++s) {
    bf16x8_t a[4], b[8];
    #pragma unroll
    for (int m = 0; m < 4; ++m)
      a[m] = *(const bf16x8_t*)&xs[(m * 16 + lr) * LDS_STRIDE + s * 32 + lg * 8];
    #pragma unroll
    for (int n = 0; n < 8; ++n)
      b[n] = *(const bf16x8_t*)&Wkp[(n * 16 + lr) * INC + s * 32 + lg * 8];
    #pragma unroll
    for (int m = 0; m < 4; ++m)
      #pragma unroll
      for (int n = 0; n < 8; ++n)
        accr[m][n] = __builtin_amdgcn_mfma_f32_16x16x32_bf16(a[m], b[n], accr[m][n], 0, 0, 0);
  }
  const int* oidx = out_idx + (size_t)w * N_IN;
  #pragma unroll
  for (int m = 0; m < 4; ++m) {
    int rbase = m * 16 + lg * 4;
    #pragma unroll
    for (int reg = 0; reg < 4; ++reg) {
      int grow = row0 + rbase + reg;
      if (grow < N_IN) {
        int dst = oidx[grow];
        float* ap = acc + (size_t)dst * OUTC;
        #pragma unroll
        for (int n = 0; n < 8; ++n)
          atomicAdd(&ap[n * 16 + lr], accr[m][n][reg]);
      }
    }
  }
}

__global__ void stats_f32_kernel(const float* __restrict__ acc, float* __restrict__ stats) {
  const int t = threadIdx.x;
  const int c4 = t & 31;
  const int ro = t >> 5;
  f32x4_t s = {0.f, 0.f, 0.f, 0.f}, q = {0.f, 0.f, 0.f, 0.f};
  for (int r = blockIdx.x * 8 + ro; r < N_OUT; r += gridDim.x * 8) {
    f32x4_t v = ((const f32x4_t*)acc)[(size_t)r * 32 + c4];
    s += v; q += v * v;
  }
  __shared__ float redl[256][8];
  #pragma unroll
  for (int j = 0; j < 4; ++j) { redl[t][j] = s[j]; redl[t][4 + j] = q[j]; }
  __syncthreads();
  if (t < 32) {
    float S[4] = {0.f, 0.f, 0.f, 0.f}, Q[4] = {0.f, 0.f, 0.f, 0.f};
    for (int r2 = 0; r2 < 8; ++r2)
      #pragma unroll
      for (int j = 0; j < 4; ++j) {
        S[j] += redl[r2 * 32 + t][j];
        Q[j] += redl[r2 * 32 + t][4 + j];
      }
    #pragma unroll
    for (int j = 0; j < 4; ++j) {
      atomicAdd(&stats[t * 4 + j], S[j]);
      atomicAdd(&stats[128 + t * 4 + j], Q[j]);
    }
  }
}

__global__ void norm_f32_kernel(float* __restrict__ out, const float* __restrict__ stats,
                                const float* __restrict__ gamma, const float* __restrict__ beta) {
  const int t = threadIdx.x;
  const int c4 = t & 31;
  const int ro = t >> 5;
  const float inv_n = 1.0f / (float)N_OUT;
  float sc[4], sh[4];
  #pragma unroll
  for (int j = 0; j < 4; ++j) {
    int c = c4 * 4 + j;
    float mean = stats[c] * inv_n;
    float var  = stats[128 + c] * inv_n - mean * mean;
    float s = gamma[c] * rsqrtf(var + BN_EPS);
    sc[j] = s;
    sh[j] = beta[c] - mean * s;
  }
  for (int r = blockIdx.x * 8 + ro; r < N_OUT; r += gridDim.x * 8) {
    f32x4_t v = ((const f32x4_t*)out)[(size_t)r * 32 + c4];
    #pragma unroll
    for (int j = 0; j < 4; ++j) v[j] = v[j] * sc[j] + sh[j];
    ((f32x4_t*)out)[(size_t)r * 32 + c4] = v;
  }
}

// ======================= launch =======================

extern "C" void kernel_launch(void* const* d_in, const int* in_sizes, int n_in,
                              void* d_out, int out_size, void* d_ws, size_t ws_size,
                              hipStream_t stream) {
  const float* x     = (const float*)d_in[0];
  const float* W     = (const float*)d_in[1];
  const float* gamma = (const float*)d_in[2];
  const float* beta  = (const float*)d_in[3];
  const int*   oidx  = (const int*)d_in[4];

  // ws layout (R8's, minus the slot array)
  const size_t P_OFF     = 0;                       // partials: 512,000,000
  const size_t CNT_OFF   = 512000000;               // 2,000,000
  const size_t OFFS_OFF  = 514000000;               // 2,000,384
  const size_t CURS_OFF  = 516000384;               // 2,000,000
  const size_t BSUM_OFF  = 518000384;               // 4,096
  const size_t BSUMX_OFF = 518004480;               // 4,096
  const size_t WT_OFF    = 518008576;               // 524,288
  const size_t STATS_OFF = 518532864;               // 1,024
  const size_t NEED      = 518533888;

  if (ws_size >= NEED) {
    char* ws = (char*)d_ws;
    char* partials = ws + P_OFF;
    int* cnt    = (int*)(ws + CNT_OFF);
    int* offs   = (int*)(ws + OFFS_OFF);
    int* cursor = (int*)(ws + CURS_OFF);
    int* bsum   = (int*)(ws + BSUM_OFF);
    int* bsumx  = (int*)(ws + BSUMX_OFF);
    __bf16* Wt  = (__bf16*)(ws + WT_OFF);
    float* stats = (float*)(ws + STATS_OFF);

    hipMemsetAsync(cnt, 0, N_OUT * sizeof(int), stream);
    hipMemsetAsync(stats, 0, 256 * sizeof(float), stream);

    wconv_kernel<<<(KVOL * OUTC * INC + 255) / 256, 256, 0, stream>>>(W, Wt);
    hist_kernel<<<(NTOT + 255) / 256, 256, 0, stream>>>(oidx, cnt);
    const int NB1 = (N_OUT + 1023) / 1024;  // 489
    scan1_kernel<<<NB1, 256, 0, stream>>>(cnt, offs, bsum);
    scan2_kernel<<<1, 512, 0, stream>>>(bsum, bsumx, NB1);
    scan3_kernel<<<(N_OUT + 255) / 256, 256, 0, stream>>>(offs, cursor, bsumx);
    gemm_store_kernel<<<(N_IN + TM - 1) / TM, 512, 0, stream>>>(
        x, Wt, oidx, cursor, partials);
    reduce_stats_kernel<<<2048, 256, 0, stream>>>(partials, offs, (char*)d_out, stats);
    norm_kernel<<<512, 256, 0, stream>>>((char*)d_out, stats, gamma, beta);
  } else {
    // fallback: proven round-2 atomic pipeline (needs only ~526 KB ws)
    __bf16* Wt   = (__bf16*)d_ws;
    float* stats = (float*)((char*)d_ws + (size_t)KVOL * OUTC * INC * 2);
    float* out = (float*)d_out;

    hipMemsetAsync(d_out, 0, (size_t)N_OUT * OUTC * sizeof(float), stream);
    hipMemsetAsync(stats, 0, 256 * sizeof(float), stream);

    wconv_kernel<<<(KVOL * OUTC * INC + 255) / 256, 256, 0, stream>>>(W, Wt);
    gemm_scatter_f32_kernel<<<(N_IN + TM - 1) / TM, 512, 0, stream>>>(x, Wt, oidx, out);
    stats_f32_kernel<<<1024, 256, 0, stream>>>(out, stats);
    norm_f32_kernel<<<2048, 256, 0, stream>>>(out, stats, gamma, beta);
  }
}